// Round 1
// baseline (1431.863 us; speedup 1.0000x reference)
//
#include <hip/hip_runtime.h>

// out[b][o] = sum_k x[b][k] * W[o][k];  B=2^20, K=256, O=64, fp32 in/out.
// Memory-bound: 1.342 GB mandatory HBM traffic -> ~213us floor @ 6.3 TB/s.
// Strategy: bf16 MFMA (16x16x32) so compute is ~14us and we purely stream.
// Persistent grid: 512 blocks x 4 waves = 2048 waves; 65536 row-tiles (16 rows
// each) -> 32 tiles/wave. W fragments live in 128 VGPRs per wave (loaded once).

typedef __bf16 bf16x8 __attribute__((ext_vector_type(8)));
typedef unsigned short ushort8v __attribute__((ext_vector_type(8)));
typedef float floatx4 __attribute__((ext_vector_type(4)));

#define KDIM    256
#define NDIM    64
#define NBLOCKS 512
#define TPB     256
#define NWAVES  (NBLOCKS * (TPB / 64))   // 2048
#define NTILES  ((1u << 20) / 16)        // 65536 row-tiles

__device__ __forceinline__ unsigned short f2bf(float f) {
    // round-to-nearest-even f32 -> bf16 (randn data: no NaN/Inf handling needed)
    unsigned int u = __float_as_uint(f);
    u += 0x7fffu + ((u >> 16) & 1u);
    return (unsigned short)(u >> 16);
}

__device__ __forceinline__ bf16x8 cvt8(float4 a, float4 b) {
    ushort8v u;
    u[0] = f2bf(a.x); u[1] = f2bf(a.y); u[2] = f2bf(a.z); u[3] = f2bf(a.w);
    u[4] = f2bf(b.x); u[5] = f2bf(b.y); u[6] = f2bf(b.z); u[7] = f2bf(b.w);
    return __builtin_bit_cast(bf16x8, u);
}

__global__ __launch_bounds__(TPB, 2) void NN_38010460570161_kernel(
    const float* __restrict__ x, const float* __restrict__ W,
    float* __restrict__ out)
{
    const int lane = threadIdx.x & 63;
    const int n = lane & 15;   // A-row index within tile / B-col (output) index
    const int q = lane >> 4;   // quad: selects k-offset group and C-row group
    const int wid = blockIdx.x * (TPB / 64) + (threadIdx.x >> 6);

    // ---- B fragments: B[k][n] = W[o=nt*16+n][k], lane holds k = ks*32+q*8+j ----
    bf16x8 bfrag[4][8];   // [ntile][kstep] -> 128 VGPRs
#pragma unroll
    for (int nt = 0; nt < 4; ++nt) {
        const float* wb = W + (nt * 16 + n) * KDIM + q * 8;
#pragma unroll
        for (int ks = 0; ks < 8; ++ks) {
            float4 w0 = *(const float4*)(wb + ks * 32);
            float4 w1 = *(const float4*)(wb + ks * 32 + 4);
            bfrag[nt][ks] = cvt8(w0, w1);
        }
    }

    // ---- main streaming loop over 16-row tiles ----
    for (unsigned t = wid; t < NTILES; t += NWAVES) {
        // A fragment source: x[t*16 + m][ks*32 + q*8 + j], m = lane&15
        const float* xb = x + ((size_t)(t * 16 + n)) * KDIM + q * 8;
        float4 a0[8], a1[8];
#pragma unroll
        for (int ks = 0; ks < 8; ++ks) {
            a0[ks] = *(const float4*)(xb + ks * 32);
            a1[ks] = *(const float4*)(xb + ks * 32 + 4);
        }

        floatx4 acc[4];
#pragma unroll
        for (int nt = 0; nt < 4; ++nt) acc[nt] = (floatx4){0.f, 0.f, 0.f, 0.f};

#pragma unroll
        for (int ks = 0; ks < 8; ++ks) {
            bf16x8 af = cvt8(a0[ks], a1[ks]);
#pragma unroll
            for (int nt = 0; nt < 4; ++nt)
                acc[nt] = __builtin_amdgcn_mfma_f32_16x16x32_bf16(
                    af, bfrag[nt][ks], acc[nt], 0, 0, 0);
        }

        // C/D layout: row = q*4 + r, col = lane&15 (per-ntile col base nt*16)
        float* ob = out + ((size_t)(t * 16 + q * 4)) * NDIM + n;
#pragma unroll
        for (int nt = 0; nt < 4; ++nt)
#pragma unroll
            for (int r = 0; r < 4; ++r)
                ob[(size_t)r * NDIM + nt * 16] = acc[nt][r];
    }
}

extern "C" void kernel_launch(void* const* d_in, const int* in_sizes, int n_in,
                              void* d_out, int out_size, void* d_ws, size_t ws_size,
                              hipStream_t stream) {
    const float* x = (const float*)d_in[0];    // [B, 256] fp32
    const float* W = (const float*)d_in[1];    // [64, 256] fp32
    float* out = (float*)d_out;                // [B, 64] fp32
    NN_38010460570161_kernel<<<NBLOCKS, TPB, 0, stream>>>(x, W, out);
}